// Round 2
// baseline (207.156 us; speedup 1.0000x reference)
//
#include <hip/hip_runtime.h>
#include <hip/hip_bf16.h>

// EMD loss: out[r] = sum_j ( cumsum(x[r]-y[r])[j] )^2, rows=1048576, bins=128, fp32.
// Memory-bound streaming: 1.07 GB read, 4 MB write. One wave = 2 rows
// (32 lanes/row, float4 = 4 bins per lane). All cross-lane work via DPP
// (VALU) instead of ds_bpermute shuffles to keep the LDS pipe idle.

constexpr int BINS = 128;
constexpr int F4_PER_ROW = BINS / 4;  // 32

// v + dpp_shifted(v): old=0 and bound_ctrl=1 so out-of-row / masked-off
// source lanes contribute 0.
template <int CTRL, int ROW_MASK>
__device__ __forceinline__ float dpp_add(float v) {
    int t = __builtin_amdgcn_update_dpp(0, __float_as_int(v), CTRL, ROW_MASK, 0xf, true);
    return v + __int_as_float(t);
}

// Inclusive scan over each 32-lane half of the wave (pure VALU/DPP).
__device__ __forceinline__ float scan32(float v) {
    v = dpp_add<0x111, 0xf>(v);  // row_shr:1
    v = dpp_add<0x112, 0xf>(v);  // row_shr:2
    v = dpp_add<0x114, 0xf>(v);  // row_shr:4
    v = dpp_add<0x118, 0xf>(v);  // row_shr:8  -> scan within 16-lane rows
    v = dpp_add<0x142, 0xa>(v);  // row_bcast15 into rows 1,3 -> scan within 32
    return v;
}

__global__ __launch_bounds__(256) void emd_kernel(
    const float4* __restrict__ x4, const float4* __restrict__ y4,
    float* __restrict__ out, int nrows) {
    const int tid     = blockIdx.x * blockDim.x + threadIdx.x;
    const int lane    = threadIdx.x & 63;
    const int j       = lane & 31;   // float4 index within row
    const int half    = lane >> 5;   // which of the wave's 2 rows
    const int wave    = tid >> 6;
    const int nwaves  = (gridDim.x * blockDim.x) >> 6;
    const int npairs  = nrows >> 1;  // rows handled 2-at-a-time

    for (int pair = wave; pair < npairs; pair += nwaves) {
        const int r = pair * 2 + half;          // nrows is even
        const int base = r * F4_PER_ROW + j;    // < 2^25, fits int
        const float4 xv = x4[base];
        const float4 yv = y4[base];

        // per-lane diffs and local inclusive prefix
        const float d0 = xv.x - yv.x;
        const float d1 = xv.y - yv.y;
        const float d2 = xv.z - yv.z;
        const float d3 = xv.w - yv.w;
        const float p0 = d0;
        const float p1 = p0 + d1;
        const float p2 = p1 + d2;
        const float p3 = p2 + d3;

        // inclusive scan of lane sums across the 32 lanes of this row (DPP)
        const float scan = scan32(p3);
        const float excl = scan - p3;  // exclusive prefix for this lane

        const float c0 = excl + p0;
        const float c1 = excl + p1;
        const float c2 = excl + p2;
        const float c3 = excl + p3;
        float acc = c0 * c0 + c1 * c1 + c2 * c2 + c3 * c3;

        // sum-of-squares reduction across the 32 lanes of this row:
        // inclusive scan again; lane 31 of each half holds the row total.
        acc = scan32(acc);
        if (j == 31) out[r] = acc;
    }
}

extern "C" void kernel_launch(void* const* d_in, const int* in_sizes, int n_in,
                              void* d_out, int out_size, void* d_ws, size_t ws_size,
                              hipStream_t stream) {
    const float4* x4 = (const float4*)d_in[0];
    const float4* y4 = (const float4*)d_in[1];
    float* out = (float*)d_out;
    const int nrows = out_size;  // 1048576

    const int block = 256;
    const int grid  = 2048;  // 8192 waves = 32 waves/CU, full occupancy
    emd_kernel<<<grid, block, 0, stream>>>(x4, y4, out, nrows);
}

// Round 4
// 189.365 us; speedup vs baseline: 1.0939x; 1.0939x over previous
//
#include <hip/hip_runtime.h>
#include <hip/hip_bf16.h>

// EMD loss: out[r] = sum_j ( cumsum(x[r]-y[r])[j] )^2, rows=1048576, bins=128, fp32.
// Memory-bound streaming: 1.07 GB read, 4 MB write.
// One wave = 4 rows/iteration: 2 independent 16B loads per lane per array
// (64 B/lane in flight), nontemporal (nt) to skip cache allocation on a
// read-once stream. Cross-lane work via DPP (pure VALU).

constexpr int BINS = 128;
constexpr int F4_PER_ROW = BINS / 4;  // 32

typedef float f32x4 __attribute__((ext_vector_type(4)));  // native vec for nt builtins

template <int CTRL, int ROW_MASK>
__device__ __forceinline__ float dpp_add(float v) {
    int t = __builtin_amdgcn_update_dpp(0, __float_as_int(v), CTRL, ROW_MASK, 0xf, true);
    return v + __int_as_float(t);
}

// Inclusive scan over each 32-lane half of the wave (pure VALU/DPP).
__device__ __forceinline__ float scan32(float v) {
    v = dpp_add<0x111, 0xf>(v);  // row_shr:1
    v = dpp_add<0x112, 0xf>(v);  // row_shr:2
    v = dpp_add<0x114, 0xf>(v);  // row_shr:4
    v = dpp_add<0x118, 0xf>(v);  // row_shr:8
    v = dpp_add<0x142, 0xa>(v);  // row_bcast15 into upper 16-lane rows
    return v;
}

// Full per-row pipeline for one (x,y) float4 pair -> row sum-of-squares
// (valid in lane j==31 of each 32-lane half).
__device__ __forceinline__ float row_emd(const f32x4 xv, const f32x4 yv) {
    const float d0 = xv.x - yv.x;
    const float d1 = xv.y - yv.y;
    const float d2 = xv.z - yv.z;
    const float d3 = xv.w - yv.w;
    const float p0 = d0;
    const float p1 = p0 + d1;
    const float p2 = p1 + d2;
    const float p3 = p2 + d3;
    const float scan = scan32(p3);
    const float excl = scan - p3;
    const float c0 = excl + p0;
    const float c1 = excl + p1;
    const float c2 = excl + p2;
    const float c3 = excl + p3;
    float acc = c0 * c0 + c1 * c1 + c2 * c2 + c3 * c3;
    return scan32(acc);  // lane 31 of each half holds the row total
}

__global__ __launch_bounds__(256) void emd_kernel(
    const f32x4* __restrict__ x4, const f32x4* __restrict__ y4,
    float* __restrict__ out, int nrows) {
    const int tid     = blockIdx.x * blockDim.x + threadIdx.x;
    const int lane    = threadIdx.x & 63;
    const int j       = lane & 31;
    const int half    = lane >> 5;
    const int wave    = tid >> 6;
    const int nwaves  = (gridDim.x * blockDim.x) >> 6;
    const int nquads  = nrows >> 2;  // 4 rows per wave-iteration

    for (int q = wave; q < nquads; q += nwaves) {
        const int b0 = q * (4 * F4_PER_ROW) + lane;  // rows 4q, 4q+1 (2 KB)
        const int b1 = b0 + 64;                      // rows 4q+2, 4q+3
        // issue all 4 streaming loads before any use
        const f32x4 xa = __builtin_nontemporal_load(&x4[b0]);
        const f32x4 xb = __builtin_nontemporal_load(&x4[b1]);
        const f32x4 ya = __builtin_nontemporal_load(&y4[b0]);
        const f32x4 yb = __builtin_nontemporal_load(&y4[b1]);

        const float acc0 = row_emd(xa, ya);  // row 4q + half
        const float acc1 = row_emd(xb, yb);  // row 4q + 2 + half

        if (j == 31) {
            const int r0 = q * 4 + half;
            __builtin_nontemporal_store(acc0, &out[r0]);
            __builtin_nontemporal_store(acc1, &out[r0 + 2]);
        }
    }
}

extern "C" void kernel_launch(void* const* d_in, const int* in_sizes, int n_in,
                              void* d_out, int out_size, void* d_ws, size_t ws_size,
                              hipStream_t stream) {
    const f32x4* x4 = (const f32x4*)d_in[0];
    const f32x4* y4 = (const f32x4*)d_in[1];
    float* out = (float*)d_out;
    const int nrows = out_size;  // 1048576

    const int block = 256;
    const int grid  = 2048;  // 8192 waves = full residency (256 CU x 32 waves)
    emd_kernel<<<grid, block, 0, stream>>>(x4, y4, out, nrows);
}

// Round 5
// 178.365 us; speedup vs baseline: 1.1614x; 1.0617x over previous
//
#include <hip/hip_runtime.h>
#include <hip/hip_bf16.h>

// EMD loss: out[r] = sum_j ( cumsum(x[r]-y[r])[j] )^2, rows=1048576, bins=128, fp32.
// Memory-bound streaming: 1.07 GB read, 4 MB write.
// One wave = 8 rows/iteration: 4 independent 16B loads per lane per array
// (128 B/lane in flight), nontemporal (nt) to skip cache allocation on a
// read-once stream. Cross-lane work via DPP (pure VALU).

constexpr int BINS = 128;
constexpr int F4_PER_ROW = BINS / 4;  // 32

typedef float f32x4 __attribute__((ext_vector_type(4)));  // native vec for nt builtins

template <int CTRL, int ROW_MASK>
__device__ __forceinline__ float dpp_add(float v) {
    int t = __builtin_amdgcn_update_dpp(0, __float_as_int(v), CTRL, ROW_MASK, 0xf, true);
    return v + __int_as_float(t);
}

// Inclusive scan over each 32-lane half of the wave (pure VALU/DPP).
__device__ __forceinline__ float scan32(float v) {
    v = dpp_add<0x111, 0xf>(v);  // row_shr:1
    v = dpp_add<0x112, 0xf>(v);  // row_shr:2
    v = dpp_add<0x114, 0xf>(v);  // row_shr:4
    v = dpp_add<0x118, 0xf>(v);  // row_shr:8
    v = dpp_add<0x142, 0xa>(v);  // row_bcast15 into upper 16-lane rows
    return v;
}

// Full per-row pipeline for one (x,y) float4 pair -> row sum-of-squares
// (valid in lane j==31 of each 32-lane half).
__device__ __forceinline__ float row_emd(const f32x4 xv, const f32x4 yv) {
    const float d0 = xv.x - yv.x;
    const float d1 = xv.y - yv.y;
    const float d2 = xv.z - yv.z;
    const float d3 = xv.w - yv.w;
    const float p0 = d0;
    const float p1 = p0 + d1;
    const float p2 = p1 + d2;
    const float p3 = p2 + d3;
    const float scan = scan32(p3);
    const float excl = scan - p3;
    const float c0 = excl + p0;
    const float c1 = excl + p1;
    const float c2 = excl + p2;
    const float c3 = excl + p3;
    float acc = c0 * c0 + c1 * c1 + c2 * c2 + c3 * c3;
    return scan32(acc);  // lane 31 of each half holds the row total
}

__global__ __launch_bounds__(256) void emd_kernel(
    const f32x4* __restrict__ x4, const f32x4* __restrict__ y4,
    float* __restrict__ out, int nrows) {
    const int tid     = blockIdx.x * blockDim.x + threadIdx.x;
    const int lane    = threadIdx.x & 63;
    const int j       = lane & 31;
    const int half    = lane >> 5;
    const int wave    = tid >> 6;
    const int nwaves  = (gridDim.x * blockDim.x) >> 6;
    const int nocts   = nrows >> 3;  // 8 rows per wave-iteration

    for (int q = wave; q < nocts; q += nwaves) {
        const int b0 = q * (8 * F4_PER_ROW) + lane;  // rows 8q..8q+1
        const int b1 = b0 + 64;                      // rows 8q+2..8q+3
        const int b2 = b0 + 128;                     // rows 8q+4..8q+5
        const int b3 = b0 + 192;                     // rows 8q+6..8q+7
        // issue all 8 streaming loads before any use
        const f32x4 xa = __builtin_nontemporal_load(&x4[b0]);
        const f32x4 xb = __builtin_nontemporal_load(&x4[b1]);
        const f32x4 xc = __builtin_nontemporal_load(&x4[b2]);
        const f32x4 xd = __builtin_nontemporal_load(&x4[b3]);
        const f32x4 ya = __builtin_nontemporal_load(&y4[b0]);
        const f32x4 yb = __builtin_nontemporal_load(&y4[b1]);
        const f32x4 yc = __builtin_nontemporal_load(&y4[b2]);
        const f32x4 yd = __builtin_nontemporal_load(&y4[b3]);

        const float acc0 = row_emd(xa, ya);  // row 8q     + half
        const float acc1 = row_emd(xb, yb);  // row 8q + 2 + half
        const float acc2 = row_emd(xc, yc);  // row 8q + 4 + half
        const float acc3 = row_emd(xd, yd);  // row 8q + 6 + half

        if (j == 31) {
            const int r0 = q * 8 + half;
            __builtin_nontemporal_store(acc0, &out[r0]);
            __builtin_nontemporal_store(acc1, &out[r0 + 2]);
            __builtin_nontemporal_store(acc2, &out[r0 + 4]);
            __builtin_nontemporal_store(acc3, &out[r0 + 6]);
        }
    }
}

extern "C" void kernel_launch(void* const* d_in, const int* in_sizes, int n_in,
                              void* d_out, int out_size, void* d_ws, size_t ws_size,
                              hipStream_t stream) {
    const f32x4* x4 = (const f32x4*)d_in[0];
    const f32x4* y4 = (const f32x4*)d_in[1];
    float* out = (float*)d_out;
    const int nrows = out_size;  // 1048576

    const int block = 256;
    const int grid  = 2048;  // 8192 waves = full residency (256 CU x 32 waves)
    emd_kernel<<<grid, block, 0, stream>>>(x4, y4, out, nrows);
}

// Round 6
// 168.564 us; speedup vs baseline: 1.2289x; 1.0581x over previous
//
#include <hip/hip_runtime.h>
#include <hip/hip_bf16.h>

// EMD loss: out[r] = sum_j ( cumsum(x[r]-y[r])[j] )^2, rows=1048576, bins=128, fp32.
// Memory-bound streaming: 1.07 GB read, 4 MB write.
// One wave = 16 rows/iteration: 8 independent 16B loads per lane per array
// (256 B/lane in flight), nontemporal (nt) to skip cache allocation on a
// read-once stream. Cross-lane work via DPP (pure VALU).

constexpr int BINS = 128;
constexpr int F4_PER_ROW = BINS / 4;  // 32

typedef float f32x4 __attribute__((ext_vector_type(4)));  // native vec for nt builtins

template <int CTRL, int ROW_MASK>
__device__ __forceinline__ float dpp_add(float v) {
    int t = __builtin_amdgcn_update_dpp(0, __float_as_int(v), CTRL, ROW_MASK, 0xf, true);
    return v + __int_as_float(t);
}

// Inclusive scan over each 32-lane half of the wave (pure VALU/DPP).
__device__ __forceinline__ float scan32(float v) {
    v = dpp_add<0x111, 0xf>(v);  // row_shr:1
    v = dpp_add<0x112, 0xf>(v);  // row_shr:2
    v = dpp_add<0x114, 0xf>(v);  // row_shr:4
    v = dpp_add<0x118, 0xf>(v);  // row_shr:8
    v = dpp_add<0x142, 0xa>(v);  // row_bcast15 into upper 16-lane rows
    return v;
}

// Full per-row pipeline for one (x,y) float4 pair -> row sum-of-squares
// (valid in lane j==31 of each 32-lane half).
__device__ __forceinline__ float row_emd(const f32x4 xv, const f32x4 yv) {
    const float d0 = xv.x - yv.x;
    const float d1 = xv.y - yv.y;
    const float d2 = xv.z - yv.z;
    const float d3 = xv.w - yv.w;
    const float p0 = d0;
    const float p1 = p0 + d1;
    const float p2 = p1 + d2;
    const float p3 = p2 + d3;
    const float scan = scan32(p3);
    const float excl = scan - p3;
    const float c0 = excl + p0;
    const float c1 = excl + p1;
    const float c2 = excl + p2;
    const float c3 = excl + p3;
    float acc = c0 * c0 + c1 * c1 + c2 * c2 + c3 * c3;
    return scan32(acc);  // lane 31 of each half holds the row total
}

__global__ __launch_bounds__(256) void emd_kernel(
    const f32x4* __restrict__ x4, const f32x4* __restrict__ y4,
    float* __restrict__ out, int nrows) {
    const int tid     = blockIdx.x * blockDim.x + threadIdx.x;
    const int lane    = threadIdx.x & 63;
    const int j       = lane & 31;
    const int half    = lane >> 5;
    const int wave    = tid >> 6;
    const int nwaves  = (gridDim.x * blockDim.x) >> 6;
    const int ngrp    = nrows >> 4;  // 16 rows per wave-iteration

    for (int q = wave; q < ngrp; q += nwaves) {
        const int b = q * (16 * F4_PER_ROW) + lane;  // rows 16q..16q+1 base
        f32x4 xv[8], yv[8];
        // issue all 16 streaming loads before any use
        #pragma unroll
        for (int k = 0; k < 8; ++k) xv[k] = __builtin_nontemporal_load(&x4[b + 64 * k]);
        #pragma unroll
        for (int k = 0; k < 8; ++k) yv[k] = __builtin_nontemporal_load(&y4[b + 64 * k]);

        float acc[8];
        #pragma unroll
        for (int k = 0; k < 8; ++k) acc[k] = row_emd(xv[k], yv[k]);  // row 16q + 2k + half

        if (j == 31) {
            const int r0 = q * 16 + half;
            #pragma unroll
            for (int k = 0; k < 8; ++k)
                __builtin_nontemporal_store(acc[k], &out[r0 + 2 * k]);
        }
    }
}

extern "C" void kernel_launch(void* const* d_in, const int* in_sizes, int n_in,
                              void* d_out, int out_size, void* d_ws, size_t ws_size,
                              hipStream_t stream) {
    const f32x4* x4 = (const f32x4*)d_in[0];
    const f32x4* y4 = (const f32x4*)d_in[1];
    float* out = (float*)d_out;
    const int nrows = out_size;  // 1048576

    const int block = 256;
    const int grid  = 2048;  // 8192 waves = full residency (256 CU x 32 waves)
    emd_kernel<<<grid, block, 0, stream>>>(x4, y4, out, nrows);
}